// Round 8
// baseline (378.310 us; speedup 1.0000x reference)
//
#include <hip/hip_runtime.h>
#include <math.h>

// EquiGroupSamplingIco — round 8:
//  - k_mm2 v3: 128x128 tile + SPLIT-K=2 (grid 512 = 2 blocks/CU; R7's grid-256
//    = 1/CU exposed ~1700 cyc/iter of barrier latency). B-fragments now load
//    global->VGPR (reg-dbuf) — B removed from LDS, halving LDS bytes/block-iter
//    (96->48 KB). Blocks write fp32 partials; new k_red sums splits + does the
//    Abuf scatter. ws evidence (harness fill = 262,144 KB) says ws = 256 MiB;
//    gate on 116 MB with R7-combined fallback.
//  - k_pre / k_sig / k_batchX / k_icoT unchanged (proven).

#define NBT  512
#define F8c  16
#define F2c  64
#define GJ   455
#define GG   4096
#define NICO 60
#define JP   512      // padded j for trajbf / icoB

typedef short bf16x8 __attribute__((ext_vector_type(8)));
typedef float f32x4  __attribute__((ext_vector_type(4)));
typedef unsigned int u32;
typedef unsigned short ushort;

struct W7 { const float* p[7]; };

__device__ __forceinline__ ushort f2bf(float f) {
  u32 u = __float_as_uint(f);
  return (ushort)((u + 0x7fffu + ((u >> 16) & 1u)) >> 16);   // RNE
}

__device__ __forceinline__ int sel7(int l, int a0, int a1, int a2, int a3,
                                    int a4, int a5, int a6) {
  int r = a6;
  r = (l == 5) ? a5 : r; r = (l == 4) ? a4 : r; r = (l == 3) ? a3 : r;
  r = (l == 2) ? a2 : r; r = (l == 1) ? a1 : r; r = (l == 0) ? a0 : r;
  return r;
}
__device__ __forceinline__ float sel7f(int l, float a0, float a1, float a2,
                                       float a3, float a4, float a5, float a6) {
  float r = a6;
  r = (l == 5) ? a5 : r; r = (l == 4) ? a4 : r; r = (l == 3) ? a3 : r;
  r = (l == 2) ? a2 : r; r = (l == 1) ? a1 : r; r = (l == 0) ? a0 : r;
  return r;
}

// ---------------- k_pre: fused preprocessing (unchanged from R7) ----------------
__global__ __launch_bounds__(256) void k_pre(const float* __restrict__ traj,
                                             const float* __restrict__ w1s,
                                             const float* __restrict__ w1v,
                                             const float* __restrict__ ico,
                                             const float* __restrict__ Dout,
                                             W7 w2,
                                             float* __restrict__ h,
                                             ushort* __restrict__ icoB,
                                             ushort* __restrict__ DoutBT,
                                             ushort* __restrict__ Abuf,
                                             ushort* __restrict__ Bbuf) {
  __shared__ float t[64][65];
  int b = blockIdx.x, tid = threadIdx.x;
  if (b < 2240) {
    ((uint4*)Abuf)[b * 256 + tid] = (uint4){0, 0, 0, 0};
  } else if (b < 2752) {
    int b2 = b - 2240;
    int jt = b2 & 7, kt = b2 >> 3;
    int tx = tid & 63, ty = tid >> 6;
    #pragma unroll
    for (int i = 0; i < 16; ++i) {
      int r = i * 4 + ty, j = jt * 64 + tx;
      t[r][tx] = (j < GJ) ? Dout[(size_t)(kt * 64 + r) * GJ + j] : 0.f;
    }
    __syncthreads();
    #pragma unroll
    for (int i = 0; i < 16; ++i) {
      int jl = i * 4 + ty;
      DoutBT[(size_t)(jt * 64 + jl) * GG + kt * 64 + tx] = f2bf(t[tx][jl]);
    }
  } else if (b < 4992) {
    int ee = (b - 2752) * 256 + tid;
    if (ee < 573440) {
      int l = (ee >= 4096) + (ee >= 16384) + (ee >= 57344) + (ee >= 114688) +
              (ee >= 225280) + (ee >= 360448);
      int base = sel7(l, 0, 4096, 16384, 57344, 114688, 225280, 360448);
      int d    = sel7(l, 1, 3, 5, 7, 9, 11, 13);
      int Kp   = sel7(l, 64, 64, 128, 128, 192, 192, 256);
      int local = ee - base;
      int row = local / Kp, kcol = local - row * Kp;
      int g2 = row / d, v = row - g2 * d;
      ushort val = 0;
      if (kcol < 16 * d) {
        int f = kcol / d, u = kcol - f * d;
        const float* wl = w2.p[l];
        float scl = rsqrtf(16.f * (float)d);
        val = f2bf(wl[(((size_t)f * 64 + g2) * d + u) * d + v] * scl);
      }
      Bbuf[ee] = val;
    }
  } else if (b < 5312) {
    int idx = (b - 4992) * 256 + tid;
    if (idx < NBT * 160) {
      int bt = idx / 160, r = idx % 160, c = r / 10, i = r % 10;
      const float* tr = traj + bt * 10;
      float val;
      if (i == 0) {
        val = tr[9] * w1s[c];
      } else {
        int k = i - 1, v = k / 3, m = k % 3;
        float s = 0.f;
        #pragma unroll
        for (int u = 0; u < 3; ++u) s = fmaf(tr[u * 3 + m], w1v[c * 9 + u * 3 + v], s);
        val = s * 0.57735026918962576f;
      }
      h[idx] = val;
    }
  } else {
    int e = (b - 5312) * 256 + tid;   // 32768
    int i = e >> 9, j = e & 511;
    icoB[e] = (i < NICO && j < GJ) ? f2bf(ico[i * GJ + j]) : (ushort)0;
  }
}

// ---------------- k_sig: sigb[m][k] = bf16(relu(h[m]·Din[k])) (unchanged) ----------------
__global__ __launch_bounds__(256) void k_sig(const float* __restrict__ h,
                                             const float* __restrict__ Din,
                                             ushort* __restrict__ sigb) {
  __shared__ float hs[160];
  int tid = threadIdx.x;
  int mb = blockIdx.y;
  int kt = blockIdx.x;           // 0..1
  if (tid < 160) hs[tid] = h[mb * 160 + tid];
  float dr[80];
  const float4* dp = (const float4*)(Din + (size_t)(kt * 2048 + tid * 8) * 10);
  #pragma unroll
  for (int q = 0; q < 20; ++q) {
    float4 v = dp[q];
    dr[q * 4 + 0] = v.x; dr[q * 4 + 1] = v.y; dr[q * 4 + 2] = v.z; dr[q * 4 + 3] = v.w;
  }
  __syncthreads();
  #pragma unroll
  for (int r = 0; r < 16; ++r) {
    float hv[10];
    #pragma unroll
    for (int i = 0; i < 10; ++i) hv[i] = hs[r * 10 + i];
    bf16x8 o;
    #pragma unroll
    for (int j = 0; j < 8; ++j) {
      float s = 0.f;
      #pragma unroll
      for (int i = 0; i < 10; ++i) s = fmaf(hv[i], dr[j * 10 + i], s);
      o[j] = (short)f2bf(fmaxf(s, 0.f));
    }
    *(bf16x8*)&sigb[((size_t)(mb * 16 + r)) * GG + kt * 2048 + tid * 8] = o;
  }
}

// ---------------- k_mm2s: split-K GEMM, fp32 partials ----------------
// 128x128 tile, BK=64, SPLIT=2. grid 512: bid = nb*128 + split*64 + mb.
// A (sigb) via global_load_lds dbuf (32 KB LDS); B-frags global->VGPR reg-dbuf.
__global__ __launch_bounds__(256) void k_mm2s(const ushort* __restrict__ A,    // [8192][4096]
                                              const ushort* __restrict__ Bm,   // [512][4096]
                                              float* __restrict__ part) {      // [2][8192][512]
  __shared__ __align__(16) short Asb[2][128 * 64];   // 2 x 16 KB
  int tid = threadIdx.x;
  int lane = tid & 63, wid = tid >> 6;
  int quad = lane >> 4, lr = lane & 15;
  int wm = wid >> 1, wn = wid & 1;                   // wave tile 64x64
  int bid = blockIdx.x;
  int mb = bid & 63;
  int split = (bid >> 6) & 1;
  int nb = bid >> 7;                                 // 0..3
  int k0 = split * 2048;

  const ushort* Ab = A + (size_t)mb * 128 * GG + k0;
  const ushort* Bp = Bm + (size_t)(nb * 128 + wn * 64 + lr) * GG + k0 + quad * 8;

  f32x4 acc[4][4];
  #pragma unroll
  for (int a = 0; a < 4; ++a)
    #pragma unroll
    for (int b = 0; b < 4; ++b) acc[a][b] = (f32x4){0.f, 0.f, 0.f, 0.f};

  auto stageA = [&](int buf, int kc) {
    #pragma unroll
    for (int it = 0; it < 4; ++it) {                 // 1024 slots / 4 waves
      int s0 = (wid * 4 + it) * 64;
      int s = s0 + lane;
      int r = s >> 3, pp = s & 7, p = pp ^ (r & 7);
      __builtin_amdgcn_global_load_lds(
          (const __attribute__((address_space(1))) u32*)(Ab + (size_t)r * GG + kc + p * 8),
          (__attribute__((address_space(3))) u32*)(&Asb[buf][s0 * 8]), 16, 0, 0);
    }
  };
  bf16x8 bv[2][8];
  auto loadB = [&](int set, int kc) {
    #pragma unroll
    for (int nt = 0; nt < 4; ++nt)
      #pragma unroll
      for (int ks = 0; ks < 2; ++ks)
        bv[set][ks * 4 + nt] =
            *(const bf16x8*)(Bp + (size_t)nt * 16 * GG + kc + ks * 32);
  };

  stageA(0, 0);
  loadB(0, 0);
  __syncthreads();
  for (int it = 0; it < 32; ++it) {
    int cur = it & 1;
    if (it < 31) {                                   // prefetch in flight across compute
      stageA(cur ^ 1, (it + 1) * 64);
      loadB(cur ^ 1, (it + 1) * 64);
    }
    #pragma unroll
    for (int ks = 0; ks < 2; ++ks) {
      bf16x8 af[4];
      #pragma unroll
      for (int mt = 0; mt < 4; ++mt) {
        int ra = wm * 64 + mt * 16 + lr;
        int v = (ks * 4 + quad) ^ (ra & 7);
        af[mt] = *(const bf16x8*)&Asb[cur][(ra * 8 + v) * 8];
      }
      #pragma unroll
      for (int mt = 0; mt < 4; ++mt)
        #pragma unroll
        for (int nt = 0; nt < 4; ++nt)
          acc[mt][nt] = __builtin_amdgcn_mfma_f32_16x16x32_bf16(
              af[mt], bv[cur][ks * 4 + nt], acc[mt][nt], 0, 0, 0);
    }
    __syncthreads();
  }
  // epilogue: fp32 partial, [split][m][j], coalesced dword stores
  #pragma unroll
  for (int mt = 0; mt < 4; ++mt)
    #pragma unroll
    for (int nt = 0; nt < 4; ++nt) {
      int j = nb * 128 + wn * 64 + nt * 16 + lr;
      #pragma unroll
      for (int r = 0; r < 4; ++r) {
        int m = mb * 128 + wm * 64 + mt * 16 + quad * 4 + r;
        part[((size_t)split * 8192 + m) * 512 + j] = acc[mt][nt][r];
      }
    }
}

// ---------------- k_red: sum splits, f2bf, scatter into Abuf ----------------
__global__ __launch_bounds__(256) void k_red(const float* __restrict__ part,
                                             ushort* __restrict__ Abuf) {
  int t = blockIdx.x * 256 + threadIdx.x;            // 524288 threads, 8 el each
  int e0 = t * 8;
  int m = e0 >> 9, j0 = e0 & 511;
  const float4* p0 = (const float4*)(part + (size_t)m * 512 + j0);
  const float4* p1 = (const float4*)(part + (size_t)(8192 + m) * 512 + j0);
  float4 a0 = p0[0], a1 = p0[1], b0 = p1[0], b1 = p1[1];
  float s[8] = {a0.x + b0.x, a0.y + b0.y, a0.z + b0.z, a0.w + b0.w,
                a1.x + b1.x, a1.y + b1.y, a1.z + b1.z, a1.w + b1.w};
  int btg = m >> 4, f = m & 15;
  #pragma unroll
  for (int jj = 0; jj < 8; ++jj) {
    int j = j0 + jj;
    if (j < GJ) {
      int l = (j >= 1) + (j >= 10) + (j >= 35) + (j >= 84) + (j >= 165) + (j >= 286);
      int o    = sel7(l, 0, 1, 10, 35, 84, 165, 286);
      int d    = sel7(l, 1, 3, 5, 7, 9, 11, 13);
      int Kp   = sel7(l, 64, 64, 128, 128, 192, 192, 256);
      int Aoff = sel7(l, 0, 32768, 131072, 458752, 917504, 1802240, 2883584);
      float rcpd = sel7f(l, 1.f, 1.f / 3.f, 0.2f, 1.f / 7.f, 1.f / 9.f,
                         1.f / 11.f, 1.f / 13.f);
      int jl = j - o;
      int u = (int)(((float)jl + 0.5f) * rcpd);      // exact (margin 0.038 >> eps)
      int mB = jl - u * d;
      Abuf[(size_t)Aoff + ((size_t)btg * d + mB) * Kp + f * d + u] = f2bf(s[jj]);
    }
  }
}

// ---------------- k_mm2f: R7 combined fallback (scatter epilogue) ----------------
__global__ __launch_bounds__(256) void k_mm2f(const ushort* __restrict__ A,
                                              const ushort* __restrict__ Bm,
                                              ushort* __restrict__ Abuf) {
  __shared__ __align__(16) short Asb[2][128 * 64];
  __shared__ __align__(16) short Bsb[2][128 * 64];
  int tid = threadIdx.x;
  int lane = tid & 63, wid = tid >> 6;
  int quad = lane >> 4, lr = lane & 15;
  int wm = wid >> 1, wn = wid & 1;
  int bid = blockIdx.x;
  int mb = bid & 63, nb = bid >> 6;
  f32x4 acc[4][4];
  #pragma unroll
  for (int a = 0; a < 4; ++a)
    #pragma unroll
    for (int b = 0; b < 4; ++b) acc[a][b] = (f32x4){0.f, 0.f, 0.f, 0.f};
  const ushort* Ab = A + (size_t)mb * 128 * GG;
  const ushort* Bb = Bm + (size_t)nb * 128 * GG;
  auto stage = [&](int buf, int kc) {
    #pragma unroll
    for (int it = 0; it < 4; ++it) {
      int s0 = (wid * 4 + it) * 64;
      int s = s0 + lane;
      int r = s >> 3, pp = s & 7, p = pp ^ (r & 7);
      __builtin_amdgcn_global_load_lds(
          (const __attribute__((address_space(1))) u32*)(Ab + (size_t)r * GG + kc + p * 8),
          (__attribute__((address_space(3))) u32*)(&Asb[buf][s0 * 8]), 16, 0, 0);
    }
    #pragma unroll
    for (int it = 0; it < 4; ++it) {
      int s0 = (wid * 4 + it) * 64;
      int s = s0 + lane;
      int r = s >> 3, pp = s & 7, p = pp ^ (r & 7);
      __builtin_amdgcn_global_load_lds(
          (const __attribute__((address_space(1))) u32*)(Bb + (size_t)r * GG + kc + p * 8),
          (__attribute__((address_space(3))) u32*)(&Bsb[buf][s0 * 8]), 16, 0, 0);
    }
  };
  stage(0, 0);
  __syncthreads();
  for (int it = 0; it < 64; ++it) {
    int cur = it & 1;
    if (it < 63) stage(cur ^ 1, (it + 1) * 64);
    #pragma unroll
    for (int ks = 0; ks < 2; ++ks) {
      bf16x8 af[4], bvv[4];
      #pragma unroll
      for (int mt = 0; mt < 4; ++mt) {
        int ra = wm * 64 + mt * 16 + lr;
        int v = (ks * 4 + quad) ^ (ra & 7);
        af[mt] = *(const bf16x8*)&Asb[cur][(ra * 8 + v) * 8];
      }
      #pragma unroll
      for (int nt = 0; nt < 4; ++nt) {
        int rb = wn * 64 + nt * 16 + lr;
        int v = (ks * 4 + quad) ^ (rb & 7);
        bvv[nt] = *(const bf16x8*)&Bsb[cur][(rb * 8 + v) * 8];
      }
      #pragma unroll
      for (int mt = 0; mt < 4; ++mt)
        #pragma unroll
        for (int nt = 0; nt < 4; ++nt)
          acc[mt][nt] = __builtin_amdgcn_mfma_f32_16x16x32_bf16(af[mt], bvv[nt], acc[mt][nt], 0, 0, 0);
    }
    __syncthreads();
  }
  #pragma unroll
  for (int nt = 0; nt < 4; ++nt) {
    int j = nb * 128 + wn * 64 + nt * 16 + lr;
    if (j < GJ) {
      int l = (j >= 1) + (j >= 10) + (j >= 35) + (j >= 84) + (j >= 165) + (j >= 286);
      int o    = sel7(l, 0, 1, 10, 35, 84, 165, 286);
      int d    = sel7(l, 1, 3, 5, 7, 9, 11, 13);
      int Kp   = sel7(l, 64, 64, 128, 128, 192, 192, 256);
      int Aoff = sel7(l, 0, 32768, 131072, 458752, 917504, 1802240, 2883584);
      int jl = j - o;
      float rcpd = 1.0f / (float)d;
      int u = (int)(((float)jl + 0.5f) * rcpd);
      int mB = jl - u * d;
      #pragma unroll
      for (int mt = 0; mt < 4; ++mt)
        #pragma unroll
        for (int r = 0; r < 4; ++r) {
          int m = mb * 128 + wm * 64 + mt * 16 + quad * 4 + r;
          int btg = m >> 4, f = m & 15;
          Abuf[(size_t)Aoff + ((size_t)btg * d + mB) * Kp + f * d + u] =
              f2bf(acc[mt][nt][r]);
        }
    }
  }
}

// ---------------- k_batchX: per-l GEMMs + xg GEMM (unchanged) ----------------
__global__ __launch_bounds__(256) void k_batchX(const ushort* __restrict__ Abuf,
                                                const ushort* __restrict__ Bbuf,
                                                const float* __restrict__ x,
                                                const ushort* __restrict__ icoB,
                                                ushort* __restrict__ trajbf,
                                                float* __restrict__ xg) {
  __shared__ __align__(16) short As[64 * 64];
  __shared__ __align__(16) short Bs[64 * 64];
  int bid = blockIdx.x;
  int tid = threadIdx.x;
  int lane = tid & 63, wid = tid >> 6;
  int quad = lane >> 4, lr = lane & 15;
  int wm = wid >> 1, wn = wid & 1;
  f32x4 acc[2][2];
  #pragma unroll
  for (int a = 0; a < 2; ++a)
    #pragma unroll
    for (int b = 0; b < 2; ++b) acc[a][b] = (f32x4){0.f, 0.f, 0.f, 0.f};

  if (bid >= 3640) {
    int mtile = bid - 3640;
    for (int kc = 0; kc < JP; kc += 64) {
      __syncthreads();
      #pragma unroll
      for (int it = 0; it < 2; ++it) {
        int s = it * 256 + tid;
        int r = s >> 3, p8 = s & 7, p = p8 ^ (r & 7);
        const float* xr = x + (size_t)(mtile * 64 + r) * GJ;
        int j0 = kc + p * 8;
        bf16x8 v8;
        #pragma unroll
        for (int jj = 0; jj < 8; ++jj) {
          int j = j0 + jj;
          v8[jj] = (j < GJ) ? (short)f2bf(xr[j]) : (short)0;
        }
        *(bf16x8*)&As[s * 8] = v8;
      }
      #pragma unroll
      for (int it = 0; it < 2; ++it) {
        int s0 = (wid * 2 + it) * 64;
        int s = s0 + lane;
        int r = s >> 3, p8 = s & 7, p = p8 ^ (r & 7);
        const ushort* gb = icoB + (size_t)r * JP + kc + p * 8;
        __builtin_amdgcn_global_load_lds(
            (const __attribute__((address_space(1))) u32*)gb,
            (__attribute__((address_space(3))) u32*)(Bs + s0 * 8), 16, 0, 0);
      }
      __syncthreads();
      #pragma unroll
      for (int ks = 0; ks < 2; ++ks) {
        int v = (ks * 4 + quad) ^ (lr & 7);
        bf16x8 af[2], bfv[2];
        #pragma unroll
        for (int mt = 0; mt < 2; ++mt)
          af[mt] = *(const bf16x8*)&As[(wm * 32 + mt * 16 + lr) * 64 + v * 8];
        #pragma unroll
        for (int nt = 0; nt < 2; ++nt)
          bfv[nt] = *(const bf16x8*)&Bs[(wn * 32 + nt * 16 + lr) * 64 + v * 8];
        #pragma unroll
        for (int mt = 0; mt < 2; ++mt)
          #pragma unroll
          for (int nt = 0; nt < 2; ++nt)
            acc[mt][nt] = __builtin_amdgcn_mfma_f32_16x16x32_bf16(af[mt], bfv[nt], acc[mt][nt], 0, 0, 0);
      }
    }
    #pragma unroll
    for (int mt = 0; mt < 2; ++mt)
      #pragma unroll
      for (int nt = 0; nt < 2; ++nt) {
        int i = wn * 32 + nt * 16 + lr;
        if (i < NICO) {
          #pragma unroll
          for (int r = 0; r < 4; ++r) {
            int row = mtile * 64 + wm * 32 + mt * 16 + quad * 4 + r;
            xg[(size_t)row * NICO + i] = acc[mt][nt][r];
          }
        }
      }
    return;
  }

  int l = (bid >= 8) + (bid >= 80) + (bid >= 280) + (bid >= 672) +
          (bid >= 1320) + (bid >= 2288);
  int bbase = sel7(l, 0, 8, 80, 280, 672, 1320, 2288);
  int d     = sel7(l, 1, 3, 5, 7, 9, 11, 13);
  int Kp    = sel7(l, 64, 64, 128, 128, 192, 192, 256);
  int o     = sel7(l, 0, 1, 10, 35, 84, 165, 286);
  int Aoff  = sel7(l, 0, 32768, 131072, 458752, 917504, 1802240, 2883584);
  int Boff  = sel7(l, 0, 4096, 16384, 57344, 114688, 225280, 360448);
  int t = bid - bbase;
  int mtile = t / d, ntile = t - mtile * d;

  const ushort* Ab = Abuf + Aoff;
  const ushort* Bb = Bbuf + Boff;

  for (int kc = 0; kc < Kp; kc += 64) {
    __syncthreads();
    #pragma unroll
    for (int it = 0; it < 2; ++it) {
      int s0 = (wid * 2 + it) * 64;
      int s = s0 + lane;
      int r = s >> 3, p8 = s & 7, p = p8 ^ (r & 7);
      const ushort* ga = Ab + (size_t)(mtile * 64 + r) * Kp + kc + p * 8;
      __builtin_amdgcn_global_load_lds(
          (const __attribute__((address_space(1))) u32*)ga,
          (__attribute__((address_space(3))) u32*)(As + s0 * 8), 16, 0, 0);
      const ushort* gb = Bb + (size_t)(ntile * 64 + r) * Kp + kc + p * 8;
      __builtin_amdgcn_global_load_lds(
          (const __attribute__((address_space(1))) u32*)gb,
          (__attribute__((address_space(3))) u32*)(Bs + s0 * 8), 16, 0, 0);
    }
    __syncthreads();
    #pragma unroll
    for (int ks = 0; ks < 2; ++ks) {
      int v = (ks * 4 + quad) ^ (lr & 7);
      bf16x8 af[2], bfv[2];
      #pragma unroll
      for (int mt = 0; mt < 2; ++mt)
        af[mt] = *(const bf16x8*)&As[(wm * 32 + mt * 16 + lr) * 64 + v * 8];
      #pragma unroll
      for (int nt = 0; nt < 2; ++nt)
        bfv[nt] = *(const bf16x8*)&Bs[(wn * 32 + nt * 16 + lr) * 64 + v * 8];
      #pragma unroll
      for (int mt = 0; mt < 2; ++mt)
        #pragma unroll
        for (int nt = 0; nt < 2; ++nt)
          acc[mt][nt] = __builtin_amdgcn_mfma_f32_16x16x32_bf16(af[mt], bfv[nt], acc[mt][nt], 0, 0, 0);
    }
  }
  #pragma unroll
  for (int mt = 0; mt < 2; ++mt)
    #pragma unroll
    for (int nt = 0; nt < 2; ++nt)
      #pragma unroll
      for (int r = 0; r < 4; ++r) {
        int Mrow = mtile * 64 + wm * 32 + mt * 16 + quad * 4 + r;
        int Ncol = ntile * 64 + wn * 32 + nt * 16 + lr;
        int bt = Mrow / d, m = Mrow - bt * d;
        int g2 = Ncol / d, v = Ncol - g2 * d;
        trajbf[(size_t)(bt * 64 + g2) * JP + o + v * d + m] = f2bf(acc[mt][nt][r]);
      }
}

// ---------------- k_icoT: trajo = trajbf · icoB^T (unchanged) ----------------
__global__ __launch_bounds__(256) void k_icoT(const ushort* __restrict__ trajbf,
                                              const ushort* __restrict__ icoB,
                                              float* __restrict__ trajo) {
  __shared__ __align__(16) short As[64 * 64];
  __shared__ __align__(16) short Bs[64 * 64];
  int mtile = blockIdx.x;
  int tid = threadIdx.x;
  int lane = tid & 63, wid = tid >> 6;
  int quad = lane >> 4, lr = lane & 15;
  int wm = wid >> 1, wn = wid & 1;
  f32x4 acc[2][2];
  #pragma unroll
  for (int a = 0; a < 2; ++a)
    #pragma unroll
    for (int b = 0; b < 2; ++b) acc[a][b] = (f32x4){0.f, 0.f, 0.f, 0.f};
  for (int kc = 0; kc < JP; kc += 64) {
    __syncthreads();
    #pragma unroll
    for (int it = 0; it < 2; ++it) {
      int s0 = (wid * 2 + it) * 64;
      int s = s0 + lane;
      int r = s >> 3, p8 = s & 7, p = p8 ^ (r & 7);
      const ushort* ga = trajbf + (size_t)(mtile * 64 + r) * JP + kc + p * 8;
      __builtin_amdgcn_global_load_lds(
          (const __attribute__((address_space(1))) u32*)ga,
          (__attribute__((address_space(3))) u32*)(As + s0 * 8), 16, 0, 0);
      const ushort* gb = icoB + (size_t)r * JP + kc + p * 8;
      __builtin_amdgcn_global_load_lds(
          (const __attribute__((address_space(1))) u32*)gb,
          (__attribute__((address_space(3))) u32*)(Bs + s0 * 8), 16, 0, 0);
    }
    __syncthreads();
    #pragma unroll
    for (int ks = 0; ks < 2; ++ks) {
      int v = (ks * 4 + quad) ^ (lr & 7);
      bf16x8 af[2], bfv[2];
      #pragma unroll
      for (int mt = 0; mt < 2; ++mt)
        af[mt] = *(const bf16x8*)&As[(wm * 32 + mt * 16 + lr) * 64 + v * 8];
      #pragma unroll
      for (int nt = 0; nt < 2; ++nt)
        bfv[nt] = *(const bf16x8*)&Bs[(wn * 32 + nt * 16 + lr) * 64 + v * 8];
      #pragma unroll
      for (int mt = 0; mt < 2; ++mt)
        #pragma unroll
        for (int nt = 0; nt < 2; ++nt)
          acc[mt][nt] = __builtin_amdgcn_mfma_f32_16x16x32_bf16(af[mt], bfv[nt], acc[mt][nt], 0, 0, 0);
    }
  }
  #pragma unroll
  for (int mt = 0; mt < 2; ++mt)
    #pragma unroll
    for (int nt = 0; nt < 2; ++nt) {
      int i = wn * 32 + nt * 16 + lr;
      if (i < NICO) {
        #pragma unroll
        for (int r = 0; r < 4; ++r) {
          int row = mtile * 64 + wm * 32 + mt * 16 + quad * 4 + r;
          trajo[(size_t)row * NICO + i] = acc[mt][nt][r];
        }
      }
    }
}

extern "C" void kernel_launch(void* const* d_in, const int* in_sizes, int n_in,
                              void* d_out, int out_size, void* d_ws, size_t ws_size,
                              hipStream_t stream) {
  const float *x = nullptr, *traj = nullptr, *w1s = nullptr, *w1v = nullptr;
  const float *Din = nullptr, *Dout = nullptr, *ico = nullptr;
  W7 w2{};
  for (int i = 0; i < n_in; ++i) {
    const float* p = (const float*)d_in[i];
    switch (in_sizes[i]) {
      case 7454720: x = p; break;
      case 5120:    traj = p; break;
      case 16:      w1s = p; break;
      case 144:     w1v = p; break;
      case 40960:   Din = p; break;
      case 1863680: Dout = p; break;
      case 27300:   ico = p; break;
      case 1024:    w2.p[0] = p; break;
      case 9216:    w2.p[1] = p; break;
      case 25600:   w2.p[2] = p; break;
      case 50176:   w2.p[3] = p; break;
      case 82944:   w2.p[4] = p; break;
      case 123904:  w2.p[5] = p; break;
      case 173056:  w2.p[6] = p; break;
      default: break;
    }
  }
  // ws layout (bytes):
  //   h       @ 0            (327,680)
  //   DoutBT  @ 327,680      (4,194,304)
  //   icoB    @ 4,521,984    (65,536)
  //   Abuf    @ 4,587,520    (9,175,040)
  //   Bbuf    @ 13,762,560   (1,146,880)
  //   sigb    @ 14,909,440   (67,108,864)  [trajbf aliases this]
  //   part    @ 82,018,304   (33,554,432)  -> total 115,572,736
  char* wsb = (char*)d_ws;
  float*  h       = (float*)wsb;
  ushort* DoutBT  = (ushort*)(wsb + 327680);
  ushort* icoB    = (ushort*)(wsb + 4521984);
  ushort* Abuf    = (ushort*)(wsb + 4587520);
  ushort* Bbuf    = (ushort*)(wsb + 13762560);
  ushort* sigb    = (ushort*)(wsb + 14909440);
  ushort* trajbf  = sigb;
  float*  part    = (float*)(wsb + 82018304);
  float* xg    = (float*)d_out;
  float* trajo = (float*)d_out + 983040;

  k_pre<<<dim3(5440), dim3(256), 0, stream>>>(traj, w1s, w1v, ico, Dout, w2,
                                              h, icoB, DoutBT, Abuf, Bbuf);
  k_sig<<<dim3(2, 512), dim3(256), 0, stream>>>(h, Din, sigb);
  if (ws_size >= 115572736ULL) {
    k_mm2s<<<dim3(512),  dim3(256), 0, stream>>>(sigb, DoutBT, part);
    k_red <<<dim3(2048), dim3(256), 0, stream>>>(part, Abuf);
  } else {
    k_mm2f<<<dim3(256),  dim3(256), 0, stream>>>(sigb, DoutBT, Abuf);   // R7 path
  }
  k_batchX<<<dim3(3896), dim3(256), 0, stream>>>(Abuf, Bbuf, x, icoB, trajbf, xg);
  k_icoT  <<<dim3(512),  dim3(256), 0, stream>>>(trajbf, icoB, trajo);
}

// Round 9
// 234.373 us; speedup vs baseline: 1.6141x; 1.6141x over previous
//
#include <hip/hip_runtime.h>
#include <math.h>

// EquiGroupSamplingIco — round 9:
//  R8 post-mortem: B-in-registers (bv[2][8]=64 VGPR) SPILLED to scratch
//  (VGPR_Count 88 < live set; WRITE_SIZE 528 MB of scratch traffic). Split-K=2
//  and k_red were correct and are kept. k_mm2s v2 = R7's proven LDS dbuf
//  staging for BOTH operands (64 KB -> 2 blocks/CU at grid 512) + split-K.
//  Everything else identical to R8 (which passed).

#define NBT  512
#define F8c  16
#define F2c  64
#define GJ   455
#define GG   4096
#define NICO 60
#define JP   512      // padded j for trajbf / icoB

typedef short bf16x8 __attribute__((ext_vector_type(8)));
typedef float f32x4  __attribute__((ext_vector_type(4)));
typedef unsigned int u32;
typedef unsigned short ushort;

struct W7 { const float* p[7]; };

__device__ __forceinline__ ushort f2bf(float f) {
  u32 u = __float_as_uint(f);
  return (ushort)((u + 0x7fffu + ((u >> 16) & 1u)) >> 16);   // RNE
}

__device__ __forceinline__ int sel7(int l, int a0, int a1, int a2, int a3,
                                    int a4, int a5, int a6) {
  int r = a6;
  r = (l == 5) ? a5 : r; r = (l == 4) ? a4 : r; r = (l == 3) ? a3 : r;
  r = (l == 2) ? a2 : r; r = (l == 1) ? a1 : r; r = (l == 0) ? a0 : r;
  return r;
}
__device__ __forceinline__ float sel7f(int l, float a0, float a1, float a2,
                                       float a3, float a4, float a5, float a6) {
  float r = a6;
  r = (l == 5) ? a5 : r; r = (l == 4) ? a4 : r; r = (l == 3) ? a3 : r;
  r = (l == 2) ? a2 : r; r = (l == 1) ? a1 : r; r = (l == 0) ? a0 : r;
  return r;
}

// ---------------- k_pre: fused preprocessing (unchanged) ----------------
__global__ __launch_bounds__(256) void k_pre(const float* __restrict__ traj,
                                             const float* __restrict__ w1s,
                                             const float* __restrict__ w1v,
                                             const float* __restrict__ ico,
                                             const float* __restrict__ Dout,
                                             W7 w2,
                                             float* __restrict__ h,
                                             ushort* __restrict__ icoB,
                                             ushort* __restrict__ DoutBT,
                                             ushort* __restrict__ Abuf,
                                             ushort* __restrict__ Bbuf) {
  __shared__ float t[64][65];
  int b = blockIdx.x, tid = threadIdx.x;
  if (b < 2240) {
    ((uint4*)Abuf)[b * 256 + tid] = (uint4){0, 0, 0, 0};
  } else if (b < 2752) {
    int b2 = b - 2240;
    int jt = b2 & 7, kt = b2 >> 3;
    int tx = tid & 63, ty = tid >> 6;
    #pragma unroll
    for (int i = 0; i < 16; ++i) {
      int r = i * 4 + ty, j = jt * 64 + tx;
      t[r][tx] = (j < GJ) ? Dout[(size_t)(kt * 64 + r) * GJ + j] : 0.f;
    }
    __syncthreads();
    #pragma unroll
    for (int i = 0; i < 16; ++i) {
      int jl = i * 4 + ty;
      DoutBT[(size_t)(jt * 64 + jl) * GG + kt * 64 + tx] = f2bf(t[tx][jl]);
    }
  } else if (b < 4992) {
    int ee = (b - 2752) * 256 + tid;
    if (ee < 573440) {
      int l = (ee >= 4096) + (ee >= 16384) + (ee >= 57344) + (ee >= 114688) +
              (ee >= 225280) + (ee >= 360448);
      int base = sel7(l, 0, 4096, 16384, 57344, 114688, 225280, 360448);
      int d    = sel7(l, 1, 3, 5, 7, 9, 11, 13);
      int Kp   = sel7(l, 64, 64, 128, 128, 192, 192, 256);
      int local = ee - base;
      int row = local / Kp, kcol = local - row * Kp;
      int g2 = row / d, v = row - g2 * d;
      ushort val = 0;
      if (kcol < 16 * d) {
        int f = kcol / d, u = kcol - f * d;
        const float* wl = w2.p[l];
        float scl = rsqrtf(16.f * (float)d);
        val = f2bf(wl[(((size_t)f * 64 + g2) * d + u) * d + v] * scl);
      }
      Bbuf[ee] = val;
    }
  } else if (b < 5312) {
    int idx = (b - 4992) * 256 + tid;
    if (idx < NBT * 160) {
      int bt = idx / 160, r = idx % 160, c = r / 10, i = r % 10;
      const float* tr = traj + bt * 10;
      float val;
      if (i == 0) {
        val = tr[9] * w1s[c];
      } else {
        int k = i - 1, v = k / 3, m = k % 3;
        float s = 0.f;
        #pragma unroll
        for (int u = 0; u < 3; ++u) s = fmaf(tr[u * 3 + m], w1v[c * 9 + u * 3 + v], s);
        val = s * 0.57735026918962576f;
      }
      h[idx] = val;
    }
  } else {
    int e = (b - 5312) * 256 + tid;   // 32768
    int i = e >> 9, j = e & 511;
    icoB[e] = (i < NICO && j < GJ) ? f2bf(ico[i * GJ + j]) : (ushort)0;
  }
}

// ---------------- k_sig (unchanged) ----------------
__global__ __launch_bounds__(256) void k_sig(const float* __restrict__ h,
                                             const float* __restrict__ Din,
                                             ushort* __restrict__ sigb) {
  __shared__ float hs[160];
  int tid = threadIdx.x;
  int mb = blockIdx.y;
  int kt = blockIdx.x;           // 0..1
  if (tid < 160) hs[tid] = h[mb * 160 + tid];
  float dr[80];
  const float4* dp = (const float4*)(Din + (size_t)(kt * 2048 + tid * 8) * 10);
  #pragma unroll
  for (int q = 0; q < 20; ++q) {
    float4 v = dp[q];
    dr[q * 4 + 0] = v.x; dr[q * 4 + 1] = v.y; dr[q * 4 + 2] = v.z; dr[q * 4 + 3] = v.w;
  }
  __syncthreads();
  #pragma unroll
  for (int r = 0; r < 16; ++r) {
    float hv[10];
    #pragma unroll
    for (int i = 0; i < 10; ++i) hv[i] = hs[r * 10 + i];
    bf16x8 o;
    #pragma unroll
    for (int j = 0; j < 8; ++j) {
      float s = 0.f;
      #pragma unroll
      for (int i = 0; i < 10; ++i) s = fmaf(hv[i], dr[j * 10 + i], s);
      o[j] = (short)f2bf(fmaxf(s, 0.f));
    }
    *(bf16x8*)&sigb[((size_t)(mb * 16 + r)) * GG + kt * 2048 + tid * 8] = o;
  }
}

// ---------------- k_mm2s v2: split-K GEMM, LDS dbuf both operands ----------------
// 128x128 tile, BK=64, SPLIT=2. grid 512: bid = (nb*2+split)*64 + mb.
// LDS 64 KB (Asb+Bsb dbuf) -> 2 blocks/CU. fp32 partials to part.
__global__ __launch_bounds__(256) void k_mm2s(const ushort* __restrict__ A,    // [8192][4096]
                                              const ushort* __restrict__ Bm,   // [512][4096]
                                              float* __restrict__ part) {      // [2][8192][512]
  __shared__ __align__(16) short Asb[2][128 * 64];   // 2 x 16 KB
  __shared__ __align__(16) short Bsb[2][128 * 64];   // 2 x 16 KB
  int tid = threadIdx.x;
  int lane = tid & 63, wid = tid >> 6;
  int quad = lane >> 4, lr = lane & 15;
  int wm = wid >> 1, wn = wid & 1;                   // wave tile 64x64
  int bid = blockIdx.x;
  int mb = bid & 63;                                 // XCD = bid%8 = mb%8
  int split = (bid >> 6) & 1;
  int nb = bid >> 7;                                 // 0..3
  int k0 = split * 2048;

  const ushort* Ab = A + (size_t)mb * 128 * GG + k0;
  const ushort* Bb = Bm + (size_t)nb * 128 * GG + k0;

  f32x4 acc[4][4];
  #pragma unroll
  for (int a = 0; a < 4; ++a)
    #pragma unroll
    for (int b = 0; b < 4; ++b) acc[a][b] = (f32x4){0.f, 0.f, 0.f, 0.f};

  auto stage = [&](int buf, int kc) {
    #pragma unroll
    for (int it = 0; it < 4; ++it) {                 // A: 1024 slots / 4 waves
      int s0 = (wid * 4 + it) * 64;
      int s = s0 + lane;
      int r = s >> 3, pp = s & 7, p = pp ^ (r & 7);
      __builtin_amdgcn_global_load_lds(
          (const __attribute__((address_space(1))) u32*)(Ab + (size_t)r * GG + kc + p * 8),
          (__attribute__((address_space(3))) u32*)(&Asb[buf][s0 * 8]), 16, 0, 0);
    }
    #pragma unroll
    for (int it = 0; it < 4; ++it) {                 // B: 1024 slots / 4 waves
      int s0 = (wid * 4 + it) * 64;
      int s = s0 + lane;
      int r = s >> 3, pp = s & 7, p = pp ^ (r & 7);
      __builtin_amdgcn_global_load_lds(
          (const __attribute__((address_space(1))) u32*)(Bb + (size_t)r * GG + kc + p * 8),
          (__attribute__((address_space(3))) u32*)(&Bsb[buf][s0 * 8]), 16, 0, 0);
    }
  };

  stage(0, 0);
  __syncthreads();
  for (int it = 0; it < 32; ++it) {
    int cur = it & 1;
    if (it < 31) stage(cur ^ 1, (it + 1) * 64);      // in flight across compute phase
    #pragma unroll
    for (int ks = 0; ks < 2; ++ks) {
      bf16x8 af[4], bv[4];
      #pragma unroll
      for (int mt = 0; mt < 4; ++mt) {
        int ra = wm * 64 + mt * 16 + lr;
        int v = (ks * 4 + quad) ^ (ra & 7);
        af[mt] = *(const bf16x8*)&Asb[cur][(ra * 8 + v) * 8];
      }
      #pragma unroll
      for (int nt = 0; nt < 4; ++nt) {
        int rb = wn * 64 + nt * 16 + lr;
        int v = (ks * 4 + quad) ^ (rb & 7);
        bv[nt] = *(const bf16x8*)&Bsb[cur][(rb * 8 + v) * 8];
      }
      #pragma unroll
      for (int mt = 0; mt < 4; ++mt)
        #pragma unroll
        for (int nt = 0; nt < 4; ++nt)
          acc[mt][nt] = __builtin_amdgcn_mfma_f32_16x16x32_bf16(af[mt], bv[nt], acc[mt][nt], 0, 0, 0);
    }
    __syncthreads();
  }
  // epilogue: fp32 partial, [split][m][j], coalesced dword stores
  #pragma unroll
  for (int mt = 0; mt < 4; ++mt)
    #pragma unroll
    for (int nt = 0; nt < 4; ++nt) {
      int j = nb * 128 + wn * 64 + nt * 16 + lr;
      #pragma unroll
      for (int r = 0; r < 4; ++r) {
        int m = mb * 128 + wm * 64 + mt * 16 + quad * 4 + r;
        part[((size_t)split * 8192 + m) * 512 + j] = acc[mt][nt][r];
      }
    }
}

// ---------------- k_red: sum splits, f2bf, scatter into Abuf (unchanged) ----------------
__global__ __launch_bounds__(256) void k_red(const float* __restrict__ part,
                                             ushort* __restrict__ Abuf) {
  int t = blockIdx.x * 256 + threadIdx.x;            // 524288 threads, 8 el each
  int e0 = t * 8;
  int m = e0 >> 9, j0 = e0 & 511;
  const float4* p0 = (const float4*)(part + (size_t)m * 512 + j0);
  const float4* p1 = (const float4*)(part + (size_t)(8192 + m) * 512 + j0);
  float4 a0 = p0[0], a1 = p0[1], b0 = p1[0], b1 = p1[1];
  float s[8] = {a0.x + b0.x, a0.y + b0.y, a0.z + b0.z, a0.w + b0.w,
                a1.x + b1.x, a1.y + b1.y, a1.z + b1.z, a1.w + b1.w};
  int btg = m >> 4, f = m & 15;
  #pragma unroll
  for (int jj = 0; jj < 8; ++jj) {
    int j = j0 + jj;
    if (j < GJ) {
      int l = (j >= 1) + (j >= 10) + (j >= 35) + (j >= 84) + (j >= 165) + (j >= 286);
      int o    = sel7(l, 0, 1, 10, 35, 84, 165, 286);
      int d    = sel7(l, 1, 3, 5, 7, 9, 11, 13);
      int Kp   = sel7(l, 64, 64, 128, 128, 192, 192, 256);
      int Aoff = sel7(l, 0, 32768, 131072, 458752, 917504, 1802240, 2883584);
      float rcpd = sel7f(l, 1.f, 1.f / 3.f, 0.2f, 1.f / 7.f, 1.f / 9.f,
                         1.f / 11.f, 1.f / 13.f);
      int jl = j - o;
      int u = (int)(((float)jl + 0.5f) * rcpd);      // exact (margin 0.038 >> eps)
      int mB = jl - u * d;
      Abuf[(size_t)Aoff + ((size_t)btg * d + mB) * Kp + f * d + u] = f2bf(s[jj]);
    }
  }
}

// ---------------- k_mm2f: R7 combined fallback (unchanged) ----------------
__global__ __launch_bounds__(256) void k_mm2f(const ushort* __restrict__ A,
                                              const ushort* __restrict__ Bm,
                                              ushort* __restrict__ Abuf) {
  __shared__ __align__(16) short Asb[2][128 * 64];
  __shared__ __align__(16) short Bsb[2][128 * 64];
  int tid = threadIdx.x;
  int lane = tid & 63, wid = tid >> 6;
  int quad = lane >> 4, lr = lane & 15;
  int wm = wid >> 1, wn = wid & 1;
  int bid = blockIdx.x;
  int mb = bid & 63, nb = bid >> 6;
  f32x4 acc[4][4];
  #pragma unroll
  for (int a = 0; a < 4; ++a)
    #pragma unroll
    for (int b = 0; b < 4; ++b) acc[a][b] = (f32x4){0.f, 0.f, 0.f, 0.f};
  const ushort* Ab = A + (size_t)mb * 128 * GG;
  const ushort* Bb = Bm + (size_t)nb * 128 * GG;
  auto stage = [&](int buf, int kc) {
    #pragma unroll
    for (int it = 0; it < 4; ++it) {
      int s0 = (wid * 4 + it) * 64;
      int s = s0 + lane;
      int r = s >> 3, pp = s & 7, p = pp ^ (r & 7);
      __builtin_amdgcn_global_load_lds(
          (const __attribute__((address_space(1))) u32*)(Ab + (size_t)r * GG + kc + p * 8),
          (__attribute__((address_space(3))) u32*)(&Asb[buf][s0 * 8]), 16, 0, 0);
    }
    #pragma unroll
    for (int it = 0; it < 4; ++it) {
      int s0 = (wid * 4 + it) * 64;
      int s = s0 + lane;
      int r = s >> 3, pp = s & 7, p = pp ^ (r & 7);
      __builtin_amdgcn_global_load_lds(
          (const __attribute__((address_space(1))) u32*)(Bb + (size_t)r * GG + kc + p * 8),
          (__attribute__((address_space(3))) u32*)(&Bsb[buf][s0 * 8]), 16, 0, 0);
    }
  };
  stage(0, 0);
  __syncthreads();
  for (int it = 0; it < 64; ++it) {
    int cur = it & 1;
    if (it < 63) stage(cur ^ 1, (it + 1) * 64);
    #pragma unroll
    for (int ks = 0; ks < 2; ++ks) {
      bf16x8 af[4], bvv[4];
      #pragma unroll
      for (int mt = 0; mt < 4; ++mt) {
        int ra = wm * 64 + mt * 16 + lr;
        int v = (ks * 4 + quad) ^ (ra & 7);
        af[mt] = *(const bf16x8*)&Asb[cur][(ra * 8 + v) * 8];
      }
      #pragma unroll
      for (int nt = 0; nt < 4; ++nt) {
        int rb = wn * 64 + nt * 16 + lr;
        int v = (ks * 4 + quad) ^ (rb & 7);
        bvv[nt] = *(const bf16x8*)&Bsb[cur][(rb * 8 + v) * 8];
      }
      #pragma unroll
      for (int mt = 0; mt < 4; ++mt)
        #pragma unroll
        for (int nt = 0; nt < 4; ++nt)
          acc[mt][nt] = __builtin_amdgcn_mfma_f32_16x16x32_bf16(af[mt], bvv[nt], acc[mt][nt], 0, 0, 0);
    }
    __syncthreads();
  }
  #pragma unroll
  for (int nt = 0; nt < 4; ++nt) {
    int j = nb * 128 + wn * 64 + nt * 16 + lr;
    if (j < GJ) {
      int l = (j >= 1) + (j >= 10) + (j >= 35) + (j >= 84) + (j >= 165) + (j >= 286);
      int o    = sel7(l, 0, 1, 10, 35, 84, 165, 286);
      int d    = sel7(l, 1, 3, 5, 7, 9, 11, 13);
      int Kp   = sel7(l, 64, 64, 128, 128, 192, 192, 256);
      int Aoff = sel7(l, 0, 32768, 131072, 458752, 917504, 1802240, 2883584);
      int jl = j - o;
      float rcpd = 1.0f / (float)d;
      int u = (int)(((float)jl + 0.5f) * rcpd);
      int mB = jl - u * d;
      #pragma unroll
      for (int mt = 0; mt < 4; ++mt)
        #pragma unroll
        for (int r = 0; r < 4; ++r) {
          int m = mb * 128 + wm * 64 + mt * 16 + quad * 4 + r;
          int btg = m >> 4, f = m & 15;
          Abuf[(size_t)Aoff + ((size_t)btg * d + mB) * Kp + f * d + u] =
              f2bf(acc[mt][nt][r]);
        }
    }
  }
}

// ---------------- k_batchX: per-l GEMMs + xg GEMM (unchanged) ----------------
__global__ __launch_bounds__(256) void k_batchX(const ushort* __restrict__ Abuf,
                                                const ushort* __restrict__ Bbuf,
                                                const float* __restrict__ x,
                                                const ushort* __restrict__ icoB,
                                                ushort* __restrict__ trajbf,
                                                float* __restrict__ xg) {
  __shared__ __align__(16) short As[64 * 64];
  __shared__ __align__(16) short Bs[64 * 64];
  int bid = blockIdx.x;
  int tid = threadIdx.x;
  int lane = tid & 63, wid = tid >> 6;
  int quad = lane >> 4, lr = lane & 15;
  int wm = wid >> 1, wn = wid & 1;
  f32x4 acc[2][2];
  #pragma unroll
  for (int a = 0; a < 2; ++a)
    #pragma unroll
    for (int b = 0; b < 2; ++b) acc[a][b] = (f32x4){0.f, 0.f, 0.f, 0.f};

  if (bid >= 3640) {
    int mtile = bid - 3640;
    for (int kc = 0; kc < JP; kc += 64) {
      __syncthreads();
      #pragma unroll
      for (int it = 0; it < 2; ++it) {
        int s = it * 256 + tid;
        int r = s >> 3, p8 = s & 7, p = p8 ^ (r & 7);
        const float* xr = x + (size_t)(mtile * 64 + r) * GJ;
        int j0 = kc + p * 8;
        bf16x8 v8;
        #pragma unroll
        for (int jj = 0; jj < 8; ++jj) {
          int j = j0 + jj;
          v8[jj] = (j < GJ) ? (short)f2bf(xr[j]) : (short)0;
        }
        *(bf16x8*)&As[s * 8] = v8;
      }
      #pragma unroll
      for (int it = 0; it < 2; ++it) {
        int s0 = (wid * 2 + it) * 64;
        int s = s0 + lane;
        int r = s >> 3, p8 = s & 7, p = p8 ^ (r & 7);
        const ushort* gb = icoB + (size_t)r * JP + kc + p * 8;
        __builtin_amdgcn_global_load_lds(
            (const __attribute__((address_space(1))) u32*)gb,
            (__attribute__((address_space(3))) u32*)(Bs + s0 * 8), 16, 0, 0);
      }
      __syncthreads();
      #pragma unroll
      for (int ks = 0; ks < 2; ++ks) {
        int v = (ks * 4 + quad) ^ (lr & 7);
        bf16x8 af[2], bfv[2];
        #pragma unroll
        for (int mt = 0; mt < 2; ++mt)
          af[mt] = *(const bf16x8*)&As[(wm * 32 + mt * 16 + lr) * 64 + v * 8];
        #pragma unroll
        for (int nt = 0; nt < 2; ++nt)
          bfv[nt] = *(const bf16x8*)&Bs[(wn * 32 + nt * 16 + lr) * 64 + v * 8];
        #pragma unroll
        for (int mt = 0; mt < 2; ++mt)
          #pragma unroll
          for (int nt = 0; nt < 2; ++nt)
            acc[mt][nt] = __builtin_amdgcn_mfma_f32_16x16x32_bf16(af[mt], bfv[nt], acc[mt][nt], 0, 0, 0);
      }
    }
    #pragma unroll
    for (int mt = 0; mt < 2; ++mt)
      #pragma unroll
      for (int nt = 0; nt < 2; ++nt) {
        int i = wn * 32 + nt * 16 + lr;
        if (i < NICO) {
          #pragma unroll
          for (int r = 0; r < 4; ++r) {
            int row = mtile * 64 + wm * 32 + mt * 16 + quad * 4 + r;
            xg[(size_t)row * NICO + i] = acc[mt][nt][r];
          }
        }
      }
    return;
  }

  int l = (bid >= 8) + (bid >= 80) + (bid >= 280) + (bid >= 672) +
          (bid >= 1320) + (bid >= 2288);
  int bbase = sel7(l, 0, 8, 80, 280, 672, 1320, 2288);
  int d     = sel7(l, 1, 3, 5, 7, 9, 11, 13);
  int Kp    = sel7(l, 64, 64, 128, 128, 192, 192, 256);
  int o     = sel7(l, 0, 1, 10, 35, 84, 165, 286);
  int Aoff  = sel7(l, 0, 32768, 131072, 458752, 917504, 1802240, 2883584);
  int Boff  = sel7(l, 0, 4096, 16384, 57344, 114688, 225280, 360448);
  int t = bid - bbase;
  int mtile = t / d, ntile = t - mtile * d;

  const ushort* Ab = Abuf + Aoff;
  const ushort* Bb = Bbuf + Boff;

  for (int kc = 0; kc < Kp; kc += 64) {
    __syncthreads();
    #pragma unroll
    for (int it = 0; it < 2; ++it) {
      int s0 = (wid * 2 + it) * 64;
      int s = s0 + lane;
      int r = s >> 3, p8 = s & 7, p = p8 ^ (r & 7);
      const ushort* ga = Ab + (size_t)(mtile * 64 + r) * Kp + kc + p * 8;
      __builtin_amdgcn_global_load_lds(
          (const __attribute__((address_space(1))) u32*)ga,
          (__attribute__((address_space(3))) u32*)(As + s0 * 8), 16, 0, 0);
      const ushort* gb = Bb + (size_t)(ntile * 64 + r) * Kp + kc + p * 8;
      __builtin_amdgcn_global_load_lds(
          (const __attribute__((address_space(1))) u32*)gb,
          (__attribute__((address_space(3))) u32*)(Bs + s0 * 8), 16, 0, 0);
    }
    __syncthreads();
    #pragma unroll
    for (int ks = 0; ks < 2; ++ks) {
      int v = (ks * 4 + quad) ^ (lr & 7);
      bf16x8 af[2], bfv[2];
      #pragma unroll
      for (int mt = 0; mt < 2; ++mt)
        af[mt] = *(const bf16x8*)&As[(wm * 32 + mt * 16 + lr) * 64 + v * 8];
      #pragma unroll
      for (int nt = 0; nt < 2; ++nt)
        bfv[nt] = *(const bf16x8*)&Bs[(wn * 32 + nt * 16 + lr) * 64 + v * 8];
      #pragma unroll
      for (int mt = 0; mt < 2; ++mt)
        #pragma unroll
        for (int nt = 0; nt < 2; ++nt)
          acc[mt][nt] = __builtin_amdgcn_mfma_f32_16x16x32_bf16(af[mt], bfv[nt], acc[mt][nt], 0, 0, 0);
    }
  }
  #pragma unroll
  for (int mt = 0; mt < 2; ++mt)
    #pragma unroll
    for (int nt = 0; nt < 2; ++nt)
      #pragma unroll
      for (int r = 0; r < 4; ++r) {
        int Mrow = mtile * 64 + wm * 32 + mt * 16 + quad * 4 + r;
        int Ncol = ntile * 64 + wn * 32 + nt * 16 + lr;
        int bt = Mrow / d, m = Mrow - bt * d;
        int g2 = Ncol / d, v = Ncol - g2 * d;
        trajbf[(size_t)(bt * 64 + g2) * JP + o + v * d + m] = f2bf(acc[mt][nt][r]);
      }
}

// ---------------- k_icoT: trajo = trajbf · icoB^T (unchanged) ----------------
__global__ __launch_bounds__(256) void k_icoT(const ushort* __restrict__ trajbf,
                                              const ushort* __restrict__ icoB,
                                              float* __restrict__ trajo) {
  __shared__ __align__(16) short As[64 * 64];
  __shared__ __align__(16) short Bs[64 * 64];
  int mtile = blockIdx.x;
  int tid = threadIdx.x;
  int lane = tid & 63, wid = tid >> 6;
  int quad = lane >> 4, lr = lane & 15;
  int wm = wid >> 1, wn = wid & 1;
  f32x4 acc[2][2];
  #pragma unroll
  for (int a = 0; a < 2; ++a)
    #pragma unroll
    for (int b = 0; b < 2; ++b) acc[a][b] = (f32x4){0.f, 0.f, 0.f, 0.f};
  for (int kc = 0; kc < JP; kc += 64) {
    __syncthreads();
    #pragma unroll
    for (int it = 0; it < 2; ++it) {
      int s0 = (wid * 2 + it) * 64;
      int s = s0 + lane;
      int r = s >> 3, p8 = s & 7, p = p8 ^ (r & 7);
      const ushort* ga = trajbf + (size_t)(mtile * 64 + r) * JP + kc + p * 8;
      __builtin_amdgcn_global_load_lds(
          (const __attribute__((address_space(1))) u32*)ga,
          (__attribute__((address_space(3))) u32*)(As + s0 * 8), 16, 0, 0);
      const ushort* gb = icoB + (size_t)r * JP + kc + p * 8;
      __builtin_amdgcn_global_load_lds(
          (const __attribute__((address_space(1))) u32*)gb,
          (__attribute__((address_space(3))) u32*)(Bs + s0 * 8), 16, 0, 0);
    }
    __syncthreads();
    #pragma unroll
    for (int ks = 0; ks < 2; ++ks) {
      int v = (ks * 4 + quad) ^ (lr & 7);
      bf16x8 af[2], bfv[2];
      #pragma unroll
      for (int mt = 0; mt < 2; ++mt)
        af[mt] = *(const bf16x8*)&As[(wm * 32 + mt * 16 + lr) * 64 + v * 8];
      #pragma unroll
      for (int nt = 0; nt < 2; ++nt)
        bfv[nt] = *(const bf16x8*)&Bs[(wn * 32 + nt * 16 + lr) * 64 + v * 8];
      #pragma unroll
      for (int mt = 0; mt < 2; ++mt)
        #pragma unroll
        for (int nt = 0; nt < 2; ++nt)
          acc[mt][nt] = __builtin_amdgcn_mfma_f32_16x16x32_bf16(af[mt], bfv[nt], acc[mt][nt], 0, 0, 0);
    }
  }
  #pragma unroll
  for (int mt = 0; mt < 2; ++mt)
    #pragma unroll
    for (int nt = 0; nt < 2; ++nt) {
      int i = wn * 32 + nt * 16 + lr;
      if (i < NICO) {
        #pragma unroll
        for (int r = 0; r < 4; ++r) {
          int row = mtile * 64 + wm * 32 + mt * 16 + quad * 4 + r;
          trajo[(size_t)row * NICO + i] = acc[mt][nt][r];
        }
      }
    }
}

extern "C" void kernel_launch(void* const* d_in, const int* in_sizes, int n_in,
                              void* d_out, int out_size, void* d_ws, size_t ws_size,
                              hipStream_t stream) {
  const float *x = nullptr, *traj = nullptr, *w1s = nullptr, *w1v = nullptr;
  const float *Din = nullptr, *Dout = nullptr, *ico = nullptr;
  W7 w2{};
  for (int i = 0; i < n_in; ++i) {
    const float* p = (const float*)d_in[i];
    switch (in_sizes[i]) {
      case 7454720: x = p; break;
      case 5120:    traj = p; break;
      case 16:      w1s = p; break;
      case 144:     w1v = p; break;
      case 40960:   Din = p; break;
      case 1863680: Dout = p; break;
      case 27300:   ico = p; break;
      case 1024:    w2.p[0] = p; break;
      case 9216:    w2.p[1] = p; break;
      case 25600:   w2.p[2] = p; break;
      case 50176:   w2.p[3] = p; break;
      case 82944:   w2.p[4] = p; break;
      case 123904:  w2.p[5] = p; break;
      case 173056:  w2.p[6] = p; break;
      default: break;
    }
  }
  // ws layout (bytes):
  //   h       @ 0            (327,680)
  //   DoutBT  @ 327,680      (4,194,304)
  //   icoB    @ 4,521,984    (65,536)
  //   Abuf    @ 4,587,520    (9,175,040)
  //   Bbuf    @ 13,762,560   (1,146,880)
  //   sigb    @ 14,909,440   (67,108,864)  [trajbf aliases this]
  //   part    @ 82,018,304   (33,554,432)  -> total 115,572,736
  char* wsb = (char*)d_ws;
  float*  h       = (float*)wsb;
  ushort* DoutBT  = (ushort*)(wsb + 327680);
  ushort* icoB    = (ushort*)(wsb + 4521984);
  ushort* Abuf    = (ushort*)(wsb + 4587520);
  ushort* Bbuf    = (ushort*)(wsb + 13762560);
  ushort* sigb    = (ushort*)(wsb + 14909440);
  ushort* trajbf  = sigb;
  float*  part    = (float*)(wsb + 82018304);
  float* xg    = (float*)d_out;
  float* trajo = (float*)d_out + 983040;

  k_pre<<<dim3(5440), dim3(256), 0, stream>>>(traj, w1s, w1v, ico, Dout, w2,
                                              h, icoB, DoutBT, Abuf, Bbuf);
  k_sig<<<dim3(2, 512), dim3(256), 0, stream>>>(h, Din, sigb);
  if (ws_size >= 115572736ULL) {
    k_mm2s<<<dim3(512),  dim3(256), 0, stream>>>(sigb, DoutBT, part);
    k_red <<<dim3(2048), dim3(256), 0, stream>>>(part, Abuf);
  } else {
    k_mm2f<<<dim3(256),  dim3(256), 0, stream>>>(sigb, DoutBT, Abuf);   // R7 path
  }
  k_batchX<<<dim3(3896), dim3(256), 0, stream>>>(Abuf, Bbuf, x, icoB, trajbf, xg);
  k_icoT  <<<dim3(512),  dim3(256), 0, stream>>>(trajbf, icoB, trajo);
}

// Round 10
// 231.059 us; speedup vs baseline: 1.6373x; 1.0143x over previous
//
#include <hip/hip_runtime.h>
#include <math.h>

// EquiGroupSamplingIco — round 10: k_batchX memory-system fixes (R9 counters:
// 52 us, FETCH 54 MB / WRITE 45 MB at 1.95 TB/s, MfmaUtil 5%).
//  1) ntile-major block decode: the d sharers of an A-chunk now land on the
//     SAME XCD (bids differ by 8d; all bbase % 8 == 0) -> A re-reads hit L2.
//  2) kappa-permuted contraction index (o + m*d + v instead of o + v*d + m) for
//     trajbf AND icoB (sum is permutation-invariant) -> trajbf writes become
//     contiguous 2d-byte runs instead of stride-2d 2B scatters. xg path keeps
//     an unpermuted icoBx copy (x is in j-order).
// All other kernels identical to R9 (passed, 234 us).

#define NBT  512
#define F8c  16
#define F2c  64
#define GJ   455
#define GG   4096
#define NICO 60
#define JP   512      // padded j for trajbf / icoB

typedef short bf16x8 __attribute__((ext_vector_type(8)));
typedef float f32x4  __attribute__((ext_vector_type(4)));
typedef unsigned int u32;
typedef unsigned short ushort;

struct W7 { const float* p[7]; };

__device__ __forceinline__ ushort f2bf(float f) {
  u32 u = __float_as_uint(f);
  return (ushort)((u + 0x7fffu + ((u >> 16) & 1u)) >> 16);   // RNE
}

__device__ __forceinline__ int sel7(int l, int a0, int a1, int a2, int a3,
                                    int a4, int a5, int a6) {
  int r = a6;
  r = (l == 5) ? a5 : r; r = (l == 4) ? a4 : r; r = (l == 3) ? a3 : r;
  r = (l == 2) ? a2 : r; r = (l == 1) ? a1 : r; r = (l == 0) ? a0 : r;
  return r;
}
__device__ __forceinline__ float sel7f(int l, float a0, float a1, float a2,
                                       float a3, float a4, float a5, float a6) {
  float r = a6;
  r = (l == 5) ? a5 : r; r = (l == 4) ? a4 : r; r = (l == 3) ? a3 : r;
  r = (l == 2) ? a2 : r; r = (l == 1) ? a1 : r; r = (l == 0) ? a0 : r;
  return r;
}

// ---------------- k_pre: fused preprocessing ----------------
// [0,2240) zero Abuf | [2240,2752) DoutBT | [2752,4992) Bbuf(w2) |
// [4992,5312) h | [5312,5440) icoB (kappa-PERMUTED) | [5440,5568) icoBx (j-order)
__global__ __launch_bounds__(256) void k_pre(const float* __restrict__ traj,
                                             const float* __restrict__ w1s,
                                             const float* __restrict__ w1v,
                                             const float* __restrict__ ico,
                                             const float* __restrict__ Dout,
                                             W7 w2,
                                             float* __restrict__ h,
                                             ushort* __restrict__ icoB,
                                             ushort* __restrict__ icoBx,
                                             ushort* __restrict__ DoutBT,
                                             ushort* __restrict__ Abuf,
                                             ushort* __restrict__ Bbuf) {
  __shared__ float t[64][65];
  int b = blockIdx.x, tid = threadIdx.x;
  if (b < 2240) {
    ((uint4*)Abuf)[b * 256 + tid] = (uint4){0, 0, 0, 0};
  } else if (b < 2752) {
    int b2 = b - 2240;
    int jt = b2 & 7, kt = b2 >> 3;
    int tx = tid & 63, ty = tid >> 6;
    #pragma unroll
    for (int i = 0; i < 16; ++i) {
      int r = i * 4 + ty, j = jt * 64 + tx;
      t[r][tx] = (j < GJ) ? Dout[(size_t)(kt * 64 + r) * GJ + j] : 0.f;
    }
    __syncthreads();
    #pragma unroll
    for (int i = 0; i < 16; ++i) {
      int jl = i * 4 + ty;
      DoutBT[(size_t)(jt * 64 + jl) * GG + kt * 64 + tx] = f2bf(t[tx][jl]);
    }
  } else if (b < 4992) {
    int ee = (b - 2752) * 256 + tid;
    if (ee < 573440) {
      int l = (ee >= 4096) + (ee >= 16384) + (ee >= 57344) + (ee >= 114688) +
              (ee >= 225280) + (ee >= 360448);
      int base = sel7(l, 0, 4096, 16384, 57344, 114688, 225280, 360448);
      int d    = sel7(l, 1, 3, 5, 7, 9, 11, 13);
      int Kp   = sel7(l, 64, 64, 128, 128, 192, 192, 256);
      int local = ee - base;
      int row = local / Kp, kcol = local - row * Kp;
      int g2 = row / d, v = row - g2 * d;
      ushort val = 0;
      if (kcol < 16 * d) {
        int f = kcol / d, u = kcol - f * d;
        const float* wl = w2.p[l];
        float scl = rsqrtf(16.f * (float)d);
        val = f2bf(wl[(((size_t)f * 64 + g2) * d + u) * d + v] * scl);
      }
      Bbuf[ee] = val;
    }
  } else if (b < 5312) {
    int idx = (b - 4992) * 256 + tid;
    if (idx < NBT * 160) {
      int bt = idx / 160, r = idx % 160, c = r / 10, i = r % 10;
      const float* tr = traj + bt * 10;
      float val;
      if (i == 0) {
        val = tr[9] * w1s[c];
      } else {
        int k = i - 1, v = k / 3, m = k % 3;
        float s = 0.f;
        #pragma unroll
        for (int u = 0; u < 3; ++u) s = fmaf(tr[u * 3 + m], w1v[c * 9 + u * 3 + v], s);
        val = s * 0.57735026918962576f;
      }
      h[idx] = val;
    }
  } else if (b < 5440) {
    // icoB, kappa-permuted: icoB[i][o + m*d + v] = ico[i][o + v*d + m]
    int e = (b - 5312) * 256 + tid;   // 32768
    int i = e >> 9, k = e & 511;
    ushort val = 0;
    if (i < NICO && k < GJ) {
      int l = (k >= 1) + (k >= 10) + (k >= 35) + (k >= 84) + (k >= 165) + (k >= 286);
      int o = sel7(l, 0, 1, 10, 35, 84, 165, 286);
      int d = sel7(l, 1, 3, 5, 7, 9, 11, 13);
      float rcpd = sel7f(l, 1.f, 1.f / 3.f, 0.2f, 1.f / 7.f, 1.f / 9.f,
                         1.f / 11.f, 1.f / 13.f);
      int local = k - o;
      int m = (int)(((float)local + 0.5f) * rcpd);   // exact (margin >> eps)
      int v = local - m * d;
      val = f2bf(ico[i * GJ + o + v * d + m]);
    }
    icoB[e] = val;
  } else {
    // icoBx, original j-order (for the xg GEMM: x is in j-order)
    int e = (b - 5440) * 256 + tid;   // 32768
    int i = e >> 9, j = e & 511;
    icoBx[e] = (i < NICO && j < GJ) ? f2bf(ico[i * GJ + j]) : (ushort)0;
  }
}

// ---------------- k_sig (unchanged) ----------------
__global__ __launch_bounds__(256) void k_sig(const float* __restrict__ h,
                                             const float* __restrict__ Din,
                                             ushort* __restrict__ sigb) {
  __shared__ float hs[160];
  int tid = threadIdx.x;
  int mb = blockIdx.y;
  int kt = blockIdx.x;           // 0..1
  if (tid < 160) hs[tid] = h[mb * 160 + tid];
  float dr[80];
  const float4* dp = (const float4*)(Din + (size_t)(kt * 2048 + tid * 8) * 10);
  #pragma unroll
  for (int q = 0; q < 20; ++q) {
    float4 v = dp[q];
    dr[q * 4 + 0] = v.x; dr[q * 4 + 1] = v.y; dr[q * 4 + 2] = v.z; dr[q * 4 + 3] = v.w;
  }
  __syncthreads();
  #pragma unroll
  for (int r = 0; r < 16; ++r) {
    float hv[10];
    #pragma unroll
    for (int i = 0; i < 10; ++i) hv[i] = hs[r * 10 + i];
    bf16x8 o;
    #pragma unroll
    for (int j = 0; j < 8; ++j) {
      float s = 0.f;
      #pragma unroll
      for (int i = 0; i < 10; ++i) s = fmaf(hv[i], dr[j * 10 + i], s);
      o[j] = (short)f2bf(fmaxf(s, 0.f));
    }
    *(bf16x8*)&sigb[((size_t)(mb * 16 + r)) * GG + kt * 2048 + tid * 8] = o;
  }
}

// ---------------- k_mm2s: split-K GEMM, LDS dbuf both operands (unchanged) ----------------
__global__ __launch_bounds__(256) void k_mm2s(const ushort* __restrict__ A,    // [8192][4096]
                                              const ushort* __restrict__ Bm,   // [512][4096]
                                              float* __restrict__ part) {      // [2][8192][512]
  __shared__ __align__(16) short Asb[2][128 * 64];   // 2 x 16 KB
  __shared__ __align__(16) short Bsb[2][128 * 64];   // 2 x 16 KB
  int tid = threadIdx.x;
  int lane = tid & 63, wid = tid >> 6;
  int quad = lane >> 4, lr = lane & 15;
  int wm = wid >> 1, wn = wid & 1;                   // wave tile 64x64
  int bid = blockIdx.x;
  int mb = bid & 63;                                 // XCD = bid%8 = mb%8
  int split = (bid >> 6) & 1;
  int nb = bid >> 7;                                 // 0..3
  int k0 = split * 2048;

  const ushort* Ab = A + (size_t)mb * 128 * GG + k0;
  const ushort* Bb = Bm + (size_t)nb * 128 * GG + k0;

  f32x4 acc[4][4];
  #pragma unroll
  for (int a = 0; a < 4; ++a)
    #pragma unroll
    for (int b = 0; b < 4; ++b) acc[a][b] = (f32x4){0.f, 0.f, 0.f, 0.f};

  auto stage = [&](int buf, int kc) {
    #pragma unroll
    for (int it = 0; it < 4; ++it) {
      int s0 = (wid * 4 + it) * 64;
      int s = s0 + lane;
      int r = s >> 3, pp = s & 7, p = pp ^ (r & 7);
      __builtin_amdgcn_global_load_lds(
          (const __attribute__((address_space(1))) u32*)(Ab + (size_t)r * GG + kc + p * 8),
          (__attribute__((address_space(3))) u32*)(&Asb[buf][s0 * 8]), 16, 0, 0);
    }
    #pragma unroll
    for (int it = 0; it < 4; ++it) {
      int s0 = (wid * 4 + it) * 64;
      int s = s0 + lane;
      int r = s >> 3, pp = s & 7, p = pp ^ (r & 7);
      __builtin_amdgcn_global_load_lds(
          (const __attribute__((address_space(1))) u32*)(Bb + (size_t)r * GG + kc + p * 8),
          (__attribute__((address_space(3))) u32*)(&Bsb[buf][s0 * 8]), 16, 0, 0);
    }
  };

  stage(0, 0);
  __syncthreads();
  for (int it = 0; it < 32; ++it) {
    int cur = it & 1;
    if (it < 31) stage(cur ^ 1, (it + 1) * 64);
    #pragma unroll
    for (int ks = 0; ks < 2; ++ks) {
      bf16x8 af[4], bv[4];
      #pragma unroll
      for (int mt = 0; mt < 4; ++mt) {
        int ra = wm * 64 + mt * 16 + lr;
        int v = (ks * 4 + quad) ^ (ra & 7);
        af[mt] = *(const bf16x8*)&Asb[cur][(ra * 8 + v) * 8];
      }
      #pragma unroll
      for (int nt = 0; nt < 4; ++nt) {
        int rb = wn * 64 + nt * 16 + lr;
        int v = (ks * 4 + quad) ^ (rb & 7);
        bv[nt] = *(const bf16x8*)&Bsb[cur][(rb * 8 + v) * 8];
      }
      #pragma unroll
      for (int mt = 0; mt < 4; ++mt)
        #pragma unroll
        for (int nt = 0; nt < 4; ++nt)
          acc[mt][nt] = __builtin_amdgcn_mfma_f32_16x16x32_bf16(af[mt], bv[nt], acc[mt][nt], 0, 0, 0);
    }
    __syncthreads();
  }
  #pragma unroll
  for (int mt = 0; mt < 4; ++mt)
    #pragma unroll
    for (int nt = 0; nt < 4; ++nt) {
      int j = nb * 128 + wn * 64 + nt * 16 + lr;
      #pragma unroll
      for (int r = 0; r < 4; ++r) {
        int m = mb * 128 + wm * 64 + mt * 16 + quad * 4 + r;
        part[((size_t)split * 8192 + m) * 512 + j] = acc[mt][nt][r];
      }
    }
}

// ---------------- k_red: sum splits, f2bf, scatter into Abuf (unchanged) ----------------
__global__ __launch_bounds__(256) void k_red(const float* __restrict__ part,
                                             ushort* __restrict__ Abuf) {
  int t = blockIdx.x * 256 + threadIdx.x;            // 524288 threads, 8 el each
  int e0 = t * 8;
  int m = e0 >> 9, j0 = e0 & 511;
  const float4* p0 = (const float4*)(part + (size_t)m * 512 + j0);
  const float4* p1 = (const float4*)(part + (size_t)(8192 + m) * 512 + j0);
  float4 a0 = p0[0], a1 = p0[1], b0 = p1[0], b1 = p1[1];
  float s[8] = {a0.x + b0.x, a0.y + b0.y, a0.z + b0.z, a0.w + b0.w,
                a1.x + b1.x, a1.y + b1.y, a1.z + b1.z, a1.w + b1.w};
  int btg = m >> 4, f = m & 15;
  #pragma unroll
  for (int jj = 0; jj < 8; ++jj) {
    int j = j0 + jj;
    if (j < GJ) {
      int l = (j >= 1) + (j >= 10) + (j >= 35) + (j >= 84) + (j >= 165) + (j >= 286);
      int o    = sel7(l, 0, 1, 10, 35, 84, 165, 286);
      int d    = sel7(l, 1, 3, 5, 7, 9, 11, 13);
      int Kp   = sel7(l, 64, 64, 128, 128, 192, 192, 256);
      int Aoff = sel7(l, 0, 32768, 131072, 458752, 917504, 1802240, 2883584);
      float rcpd = sel7f(l, 1.f, 1.f / 3.f, 0.2f, 1.f / 7.f, 1.f / 9.f,
                         1.f / 11.f, 1.f / 13.f);
      int jl = j - o;
      int u = (int)(((float)jl + 0.5f) * rcpd);
      int mB = jl - u * d;
      Abuf[(size_t)Aoff + ((size_t)btg * d + mB) * Kp + f * d + u] = f2bf(s[jj]);
    }
  }
}

// ---------------- k_mm2f: fallback combined GEMM (unchanged) ----------------
__global__ __launch_bounds__(256) void k_mm2f(const ushort* __restrict__ A,
                                              const ushort* __restrict__ Bm,
                                              ushort* __restrict__ Abuf) {
  __shared__ __align__(16) short Asb[2][128 * 64];
  __shared__ __align__(16) short Bsb[2][128 * 64];
  int tid = threadIdx.x;
  int lane = tid & 63, wid = tid >> 6;
  int quad = lane >> 4, lr = lane & 15;
  int wm = wid >> 1, wn = wid & 1;
  int bid = blockIdx.x;
  int mb = bid & 63, nb = bid >> 6;
  f32x4 acc[4][4];
  #pragma unroll
  for (int a = 0; a < 4; ++a)
    #pragma unroll
    for (int b = 0; b < 4; ++b) acc[a][b] = (f32x4){0.f, 0.f, 0.f, 0.f};
  const ushort* Ab = A + (size_t)mb * 128 * GG;
  const ushort* Bb = Bm + (size_t)nb * 128 * GG;
  auto stage = [&](int buf, int kc) {
    #pragma unroll
    for (int it = 0; it < 4; ++it) {
      int s0 = (wid * 4 + it) * 64;
      int s = s0 + lane;
      int r = s >> 3, pp = s & 7, p = pp ^ (r & 7);
      __builtin_amdgcn_global_load_lds(
          (const __attribute__((address_space(1))) u32*)(Ab + (size_t)r * GG + kc + p * 8),
          (__attribute__((address_space(3))) u32*)(&Asb[buf][s0 * 8]), 16, 0, 0);
    }
    #pragma unroll
    for (int it = 0; it < 4; ++it) {
      int s0 = (wid * 4 + it) * 64;
      int s = s0 + lane;
      int r = s >> 3, pp = s & 7, p = pp ^ (r & 7);
      __builtin_amdgcn_global_load_lds(
          (const __attribute__((address_space(1))) u32*)(Bb + (size_t)r * GG + kc + p * 8),
          (__attribute__((address_space(3))) u32*)(&Bsb[buf][s0 * 8]), 16, 0, 0);
    }
  };
  stage(0, 0);
  __syncthreads();
  for (int it = 0; it < 64; ++it) {
    int cur = it & 1;
    if (it < 63) stage(cur ^ 1, (it + 1) * 64);
    #pragma unroll
    for (int ks = 0; ks < 2; ++ks) {
      bf16x8 af[4], bvv[4];
      #pragma unroll
      for (int mt = 0; mt < 4; ++mt) {
        int ra = wm * 64 + mt * 16 + lr;
        int v = (ks * 4 + quad) ^ (ra & 7);
        af[mt] = *(const bf16x8*)&Asb[cur][(ra * 8 + v) * 8];
      }
      #pragma unroll
      for (int nt = 0; nt < 4; ++nt) {
        int rb = wn * 64 + nt * 16 + lr;
        int v = (ks * 4 + quad) ^ (rb & 7);
        bvv[nt] = *(const bf16x8*)&Bsb[cur][(rb * 8 + v) * 8];
      }
      #pragma unroll
      for (int mt = 0; mt < 4; ++mt)
        #pragma unroll
        for (int nt = 0; nt < 4; ++nt)
          acc[mt][nt] = __builtin_amdgcn_mfma_f32_16x16x32_bf16(af[mt], bvv[nt], acc[mt][nt], 0, 0, 0);
    }
    __syncthreads();
  }
  #pragma unroll
  for (int nt = 0; nt < 4; ++nt) {
    int j = nb * 128 + wn * 64 + nt * 16 + lr;
    if (j < GJ) {
      int l = (j >= 1) + (j >= 10) + (j >= 35) + (j >= 84) + (j >= 165) + (j >= 286);
      int o    = sel7(l, 0, 1, 10, 35, 84, 165, 286);
      int d    = sel7(l, 1, 3, 5, 7, 9, 11, 13);
      int Kp   = sel7(l, 64, 64, 128, 128, 192, 192, 256);
      int Aoff = sel7(l, 0, 32768, 131072, 458752, 917504, 1802240, 2883584);
      int jl = j - o;
      float rcpd = 1.0f / (float)d;
      int u = (int)(((float)jl + 0.5f) * rcpd);
      int mB = jl - u * d;
      #pragma unroll
      for (int mt = 0; mt < 4; ++mt)
        #pragma unroll
        for (int r = 0; r < 4; ++r) {
          int m = mb * 128 + wm * 64 + mt * 16 + quad * 4 + r;
          int btg = m >> 4, f = m & 15;
          Abuf[(size_t)Aoff + ((size_t)btg * d + mB) * Kp + f * d + u] =
              f2bf(acc[mt][nt][r]);
        }
    }
  }
}

// ---------------- k_batchX: per-l GEMMs (+ xg GEMM) ----------------
// ntile-major decode (A-sharers same XCD); trajbf writes kappa-permuted.
__global__ __launch_bounds__(256) void k_batchX(const ushort* __restrict__ Abuf,
                                                const ushort* __restrict__ Bbuf,
                                                const float* __restrict__ x,
                                                const ushort* __restrict__ icoBx,
                                                ushort* __restrict__ trajbf,
                                                float* __restrict__ xg) {
  __shared__ __align__(16) short As[64 * 64];
  __shared__ __align__(16) short Bs[64 * 64];
  int bid = blockIdx.x;
  int tid = threadIdx.x;
  int lane = tid & 63, wid = tid >> 6;
  int quad = lane >> 4, lr = lane & 15;
  int wm = wid >> 1, wn = wid & 1;
  f32x4 acc[2][2];
  #pragma unroll
  for (int a = 0; a < 2; ++a)
    #pragma unroll
    for (int b = 0; b < 2; ++b) acc[a][b] = (f32x4){0.f, 0.f, 0.f, 0.f};

  if (bid >= 3640) {
    int mtile = bid - 3640;
    for (int kc = 0; kc < JP; kc += 64) {
      __syncthreads();
      #pragma unroll
      for (int it = 0; it < 2; ++it) {
        int s = it * 256 + tid;
        int r = s >> 3, p8 = s & 7, p = p8 ^ (r & 7);
        const float* xr = x + (size_t)(mtile * 64 + r) * GJ;
        int j0 = kc + p * 8;
        bf16x8 v8;
        #pragma unroll
        for (int jj = 0; jj < 8; ++jj) {
          int j = j0 + jj;
          v8[jj] = (j < GJ) ? (short)f2bf(xr[j]) : (short)0;
        }
        *(bf16x8*)&As[s * 8] = v8;
      }
      #pragma unroll
      for (int it = 0; it < 2; ++it) {
        int s0 = (wid * 2 + it) * 64;
        int s = s0 + lane;
        int r = s >> 3, p8 = s & 7, p = p8 ^ (r & 7);
        const ushort* gb = icoBx + (size_t)r * JP + kc + p * 8;
        __builtin_amdgcn_global_load_lds(
            (const __attribute__((address_space(1))) u32*)gb,
            (__attribute__((address_space(3))) u32*)(Bs + s0 * 8), 16, 0, 0);
      }
      __syncthreads();
      #pragma unroll
      for (int ks = 0; ks < 2; ++ks) {
        int v = (ks * 4 + quad) ^ (lr & 7);
        bf16x8 af[2], bfv[2];
        #pragma unroll
        for (int mt = 0; mt < 2; ++mt)
          af[mt] = *(const bf16x8*)&As[(wm * 32 + mt * 16 + lr) * 64 + v * 8];
        #pragma unroll
        for (int nt = 0; nt < 2; ++nt)
          bfv[nt] = *(const bf16x8*)&Bs[(wn * 32 + nt * 16 + lr) * 64 + v * 8];
        #pragma unroll
        for (int mt = 0; mt < 2; ++mt)
          #pragma unroll
          for (int nt = 0; nt < 2; ++nt)
            acc[mt][nt] = __builtin_amdgcn_mfma_f32_16x16x32_bf16(af[mt], bfv[nt], acc[mt][nt], 0, 0, 0);
      }
    }
    #pragma unroll
    for (int mt = 0; mt < 2; ++mt)
      #pragma unroll
      for (int nt = 0; nt < 2; ++nt) {
        int i = wn * 32 + nt * 16 + lr;
        if (i < NICO) {
          #pragma unroll
          for (int r = 0; r < 4; ++r) {
            int row = mtile * 64 + wm * 32 + mt * 16 + quad * 4 + r;
            xg[(size_t)row * NICO + i] = acc[mt][nt][r];
          }
        }
      }
    return;
  }

  int l = (bid >= 8) + (bid >= 80) + (bid >= 280) + (bid >= 672) +
          (bid >= 1320) + (bid >= 2288);
  int bbase = sel7(l, 0, 8, 80, 280, 672, 1320, 2288);
  int d     = sel7(l, 1, 3, 5, 7, 9, 11, 13);
  int Kp    = sel7(l, 64, 64, 128, 128, 192, 192, 256);
  int o     = sel7(l, 0, 1, 10, 35, 84, 165, 286);
  int Aoff  = sel7(l, 0, 32768, 131072, 458752, 917504, 1802240, 2883584);
  int Boff  = sel7(l, 0, 4096, 16384, 57344, 114688, 225280, 360448);
  int t = bid - bbase;
  // ntile-major: the d sharers of mtile have t = mtile + k*8d -> bid mod 8
  // constant (bbase % 8 == 0 for all l) -> same XCD -> A re-reads hit L2.
  float rcp8d = sel7f(l, 1.f / 8.f, 1.f / 24.f, 1.f / 40.f, 1.f / 56.f,
                      1.f / 72.f, 1.f / 88.f, 1.f / 104.f);
  int ntile = (int)(((float)t + 0.5f) * rcp8d);      // exact (margin >> eps)
  int mtile = t - ntile * 8 * d;

  const ushort* Ab = Abuf + Aoff;
  const ushort* Bb = Bbuf + Boff;

  for (int kc = 0; kc < Kp; kc += 64) {
    __syncthreads();
    #pragma unroll
    for (int it = 0; it < 2; ++it) {
      int s0 = (wid * 2 + it) * 64;
      int s = s0 + lane;
      int r = s >> 3, p8 = s & 7, p = p8 ^ (r & 7);
      const ushort* ga = Ab + (size_t)(mtile * 64 + r) * Kp + kc + p * 8;
      __builtin_amdgcn_global_load_lds(
          (const __attribute__((address_space(1))) u32*)ga,
          (__attribute__((address_space(3))) u32*)(As + s0 * 8), 16, 0, 0);
      const ushort* gb = Bb + (size_t)(ntile * 64 + r) * Kp + kc + p * 8;
      __builtin_amdgcn_global_load_lds(
          (const __attribute__((address_space(1))) u32*)gb,
          (__attribute__((address_space(3))) u32*)(Bs + s0 * 8), 16, 0, 0);
    }
    __syncthreads();
    #pragma unroll
    for (int ks = 0; ks < 2; ++ks) {
      int v = (ks * 4 + quad) ^ (lr & 7);
      bf16x8 af[2], bfv[2];
      #pragma unroll
      for (int mt = 0; mt < 2; ++mt)
        af[mt] = *(const bf16x8*)&As[(wm * 32 + mt * 16 + lr) * 64 + v * 8];
      #pragma unroll
      for (int nt = 0; nt < 2; ++nt)
        bfv[nt] = *(const bf16x8*)&Bs[(wn * 32 + nt * 16 + lr) * 64 + v * 8];
      #pragma unroll
      for (int mt = 0; mt < 2; ++mt)
        #pragma unroll
        for (int nt = 0; nt < 2; ++nt)
          acc[mt][nt] = __builtin_amdgcn_mfma_f32_16x16x32_bf16(af[mt], bfv[nt], acc[mt][nt], 0, 0, 0);
    }
  }
  // kappa-permuted scatter: index o + m*d + v (consecutive v -> contiguous)
  #pragma unroll
  for (int mt = 0; mt < 2; ++mt)
    #pragma unroll
    for (int nt = 0; nt < 2; ++nt)
      #pragma unroll
      for (int r = 0; r < 4; ++r) {
        int Mrow = mtile * 64 + wm * 32 + mt * 16 + quad * 4 + r;
        int Ncol = ntile * 64 + wn * 32 + nt * 16 + lr;
        int bt = Mrow / d, m = Mrow - bt * d;
        int g2 = Ncol / d, v = Ncol - g2 * d;
        trajbf[(size_t)(bt * 64 + g2) * JP + o + m * d + v] = f2bf(acc[mt][nt][r]);
      }
}

// ---------------- k_icoT: trajo = trajbf · icoB^T (kappa-order on both; unchanged code) --
__global__ __launch_bounds__(256) void k_icoT(const ushort* __restrict__ trajbf,
                                              const ushort* __restrict__ icoB,
                                              float* __restrict__ trajo) {
  __shared__ __align__(16) short As[64 * 64];
  __shared__ __align__(16) short Bs[64 * 64];
  int mtile = blockIdx.x;
  int tid = threadIdx.x;
  int lane = tid & 63, wid = tid >> 6;
  int quad = lane >> 4, lr = lane & 15;
  int wm = wid >> 1, wn = wid & 1;
  f32x4 acc[2][2];
  #pragma unroll
  for (int a = 0; a < 2; ++a)
    #pragma unroll
    for (int b = 0; b < 2; ++b) acc[a][b] = (f32x4){0.f, 0.f, 0.f, 0.f};
  for (int kc = 0; kc < JP; kc += 64) {
    __syncthreads();
    #pragma unroll
    for (int it = 0; it < 2; ++it) {
      int s0 = (wid * 2 + it) * 64;
      int s = s0 + lane;
      int r = s >> 3, p8 = s & 7, p = p8 ^ (r & 7);
      const ushort* ga = trajbf + (size_t)(mtile * 64 + r) * JP + kc + p * 8;
      __builtin_amdgcn_global_load_lds(
          (const __attribute__((address_space(1))) u32*)ga,
          (__attribute__((address_space(3))) u32*)(As + s0 * 8), 16, 0, 0);
      const ushort* gb = icoB + (size_t)r * JP + kc + p * 8;
      __builtin_amdgcn_global_load_lds(
          (const __attribute__((address_space(1))) u32*)gb,
          (__attribute__((address_space(3))) u32*)(Bs + s0 * 8), 16, 0, 0);
    }
    __syncthreads();
    #pragma unroll
    for (int ks = 0; ks < 2; ++ks) {
      int v = (ks * 4 + quad) ^ (lr & 7);
      bf16x8 af[2], bfv[2];
      #pragma unroll
      for (int mt = 0; mt < 2; ++mt)
        af[mt] = *(const bf16x8*)&As[(wm * 32 + mt * 16 + lr) * 64 + v * 8];
      #pragma unroll
      for (int nt = 0; nt < 2; ++nt)
        bfv[nt] = *(const bf16x8*)&Bs[(wn * 32 + nt * 16 + lr) * 64 + v * 8];
      #pragma unroll
      for (int mt = 0; mt < 2; ++mt)
        #pragma unroll
        for (int nt = 0; nt < 2; ++nt)
          acc[mt][nt] = __builtin_amdgcn_mfma_f32_16x16x32_bf16(af[mt], bfv[nt], acc[mt][nt], 0, 0, 0);
    }
  }
  #pragma unroll
  for (int mt = 0; mt < 2; ++mt)
    #pragma unroll
    for (int nt = 0; nt < 2; ++nt) {
      int i = wn * 32 + nt * 16 + lr;
      if (i < NICO) {
        #pragma unroll
        for (int r = 0; r < 4; ++r) {
          int row = mtile * 64 + wm * 32 + mt * 16 + quad * 4 + r;
          trajo[(size_t)row * NICO + i] = acc[mt][nt][r];
        }
      }
    }
}

extern "C" void kernel_launch(void* const* d_in, const int* in_sizes, int n_in,
                              void* d_out, int out_size, void* d_ws, size_t ws_size,
                              hipStream_t stream) {
  const float *x = nullptr, *traj = nullptr, *w1s = nullptr, *w1v = nullptr;
  const float *Din = nullptr, *Dout = nullptr, *ico = nullptr;
  W7 w2{};
  for (int i = 0; i < n_in; ++i) {
    const float* p = (const float*)d_in[i];
    switch (in_sizes[i]) {
      case 7454720: x = p; break;
      case 5120:    traj = p; break;
      case 16:      w1s = p; break;
      case 144:     w1v = p; break;
      case 40960:   Din = p; break;
      case 1863680: Dout = p; break;
      case 27300:   ico = p; break;
      case 1024:    w2.p[0] = p; break;
      case 9216:    w2.p[1] = p; break;
      case 25600:   w2.p[2] = p; break;
      case 50176:   w2.p[3] = p; break;
      case 82944:   w2.p[4] = p; break;
      case 123904:  w2.p[5] = p; break;
      case 173056:  w2.p[6] = p; break;
      default: break;
    }
  }
  // ws layout (bytes):
  //   h       @ 0            (327,680)
  //   DoutBT  @ 327,680      (4,194,304)
  //   icoB    @ 4,521,984    (65,536)   [kappa-permuted]
  //   icoBx   @ 4,587,520    (65,536)   [j-order, for xg]
  //   Abuf    @ 4,653,056    (9,175,040)
  //   Bbuf    @ 13,828,096   (1,146,880)
  //   sigb    @ 14,974,976   (67,108,864)  [trajbf aliases this]
  //   part    @ 82,083,840   (33,554,432)  -> total 115,638,272
  char* wsb = (char*)d_ws;
  float*  h       = (float*)wsb;
  ushort* DoutBT  = (ushort*)(wsb + 327680);
  ushort* icoB    = (ushort*)(wsb + 4521984);
  ushort* icoBx   = (ushort*)(wsb + 4587520);
  ushort* Abuf    = (ushort*)(wsb + 4653056);
  ushort* Bbuf    = (ushort*)(wsb + 13828096);
  ushort* sigb    = (ushort*)(wsb + 14974976);
  ushort* trajbf  = sigb;
  float*  part    = (float*)(wsb + 82083840);
  float* xg    = (float*)d_out;
  float* trajo = (float*)d_out + 983040;

  k_pre<<<dim3(5568), dim3(256), 0, stream>>>(traj, w1s, w1v, ico, Dout, w2,
                                              h, icoB, icoBx, DoutBT, Abuf, Bbuf);
  k_sig<<<dim3(2, 512), dim3(256), 0, stream>>>(h, Din, sigb);
  if (ws_size >= 115638272ULL) {
    k_mm2s<<<dim3(512),  dim3(256), 0, stream>>>(sigb, DoutBT, part);
    k_red <<<dim3(2048), dim3(256), 0, stream>>>(part, Abuf);
  } else {
    k_mm2f<<<dim3(256),  dim3(256), 0, stream>>>(sigb, DoutBT, Abuf);
  }
  k_batchX<<<dim3(3896), dim3(256), 0, stream>>>(Abuf, Bbuf, x, icoBx, trajbf, xg);
  k_icoT  <<<dim3(512),  dim3(256), 0, stream>>>(trajbf, icoB, trajo);
}